// Round 8
// baseline (99.206 us; speedup 1.0000x reference)
//
#include <hip/hip_runtime.h>

#define NCLS 19
#define BINS 51
#define NPIX 4096
#define NFEAT 256
#define CAP 1024
#define SCROFF (CAP + 4)           // scratch slot base within a wave's segment
#define SEG (CAP + 4 + 64)         // 1092 floats per wave (16B-aligned: 4368 B)
#define NBLK (NFEAT * 9)           // 2304 blocks
#define TWO_PI_F 6.2831853071795864769f
#define LOG2E_F 1.4426950408889634f
#define EXP2F(v) __builtin_amdgcn_exp2f(v)

__device__ __forceinline__ unsigned mbcnt64(unsigned long long m) {
    unsigned r = __builtin_amdgcn_mbcnt_lo((unsigned)m, 0u);
    return __builtin_amdgcn_mbcnt_hi((unsigned)(m >> 32), r);
}

// ws layout: float partial[18*NFEAT] @ 0 (18432B); int ncls[32] @ 18432; int counter @ 18688
__global__ __launch_bounds__(128)
void hist_main(const float* __restrict__ x, const int* __restrict__ lab,
               float* __restrict__ partial, int* __restrict__ ncls,
               int* __restrict__ counter, float* __restrict__ out) {
    const int f    = blockIdx.x;
    const int tid  = threadIdx.x;
    const int lane = tid & 63;
    const int wv   = tid >> 6;                    // 0..1 — waves independent until finale
    const int c    = blockIdx.y * 2 + wv + 1;     // class 1..18

    __shared__ __align__(16) float xs[2][SEG];
    __shared__ double sd[2];
    __shared__ int s_last;
    float* xsw = xs[wv];

    const int4*   labv = (const int4*)lab;
    const float4* xvec = (const float4*)(x + (size_t)f * NPIX);

    // ---- fused scan: ballot-rank compaction into [0,CAP) + masked stats ----
    unsigned cnt = 0;
    float s1 = 0.f, s2 = 0.f;

#define SUBPX0(L, V)                                                  \
    {                                                                 \
        bool in = ((L) == c);                                         \
        unsigned long long m = __ballot(in);                          \
        unsigned g = cnt + mbcnt64(m);                                \
        int slot = (in && g < CAP) ? (int)g : (SCROFF + lane);        \
        xsw[slot] = (V);                                              \
        cnt += (unsigned)__popcll(m);                                 \
        float msk = in ? (V) : 0.f;                                   \
        s1 += msk;                                                    \
        s2 = fmaf(msk, (V), s2);                                      \
    }

    #pragma unroll 4
    for (int it = 0; it < 16; ++it) {
        int4   lv = labv[it * 64 + lane];
        float4 vv = xvec[it * 64 + lane];
        SUBPX0(lv.x, vv.x)
        SUBPX0(lv.y, vv.y)
        SUBPX0(lv.z, vv.z)
        SUBPX0(lv.w, vv.w)
    }
#undef SUBPX0

    const unsigned n = cnt;                       // wave-uniform
    if (f == 0 && lane == 0) ncls[c] = (int)n;

    if (n == 0) {
        if (lane == 0) partial[(c - 1) * NFEAT + f] = 0.f;
    } else {
        #pragma unroll
        for (int off = 32; off; off >>= 1) {
            s1 += __shfl_xor(s1, off, 64);
            s2 += __shfl_xor(s2, off, 64);
        }
        const float fn  = (float)n;
        const float miu = s1 / fn;
        const float var = fmaxf(s2 / fn - miu * miu, 1e-12f);

        // ---- KDE: lane = bin; 4 exp2 chains over LDS float4 broadcast reads ----
        const float binv  = -5.0f + 0.2f * (float)lane;
        const float coef2 = (-12.5f / var) * LOG2E_F;     // -0.5/(var*0.04)*log2e
        float a0 = 0.f, a1 = 0.f, a2 = 0.f, a3 = 0.f;

        for (unsigned t0 = 0; t0 < n; t0 += CAP) {
            if (t0 > 0) {                         // rare window rescan (n > CAP)
                unsigned c2 = 0;
                for (int it = 0; it < 16; ++it) {
                    int4   lv = labv[it * 64 + lane];
                    float4 vv = xvec[it * 64 + lane];
#define SUBPXW(L, V)                                                  \
    {                                                                 \
        bool in = ((L) == c);                                         \
        unsigned long long m = __ballot(in);                          \
        unsigned g = c2 + mbcnt64(m) - t0;                            \
        int slot = (in && g < CAP) ? (int)g : (SCROFF + lane);        \
        xsw[slot] = (V);                                              \
        c2 += (unsigned)__popcll(m);                                  \
    }
                    SUBPXW(lv.x, vv.x)
                    SUBPXW(lv.y, vv.y)
                    SUBPXW(lv.z, vv.z)
                    SUBPXW(lv.w, vv.w)
#undef SUBPXW
                }
            }
            int ns  = (int)((n - t0 < CAP) ? (n - t0) : CAP);
            int ns4 = (ns + 3) & ~3;
            if (lane < ns4 - ns) xsw[ns + lane] = 1e19f;   // sentinel: exp2 -> 0
            for (int i = 0; i < ns4; i += 4) {
                float4 v = *(const float4*)&xsw[i];        // same-addr broadcast
                float d0 = binv - v.x, d1 = binv - v.y, d2 = binv - v.z, d3 = binv - v.w;
                a0 += EXP2F(coef2 * (d0 * d0));
                a1 += EXP2F(coef2 * (d1 * d1));
                a2 += EXP2F(coef2 * (d2 * d2));
                a3 += EXP2F(coef2 * (d3 * d3));
            }
        }

        // ---- normalize + smooth-L1 (single wave, lane = bin) ----
        float kde = (a0 + a1) + (a2 + a3);
        float vs  = var * 0.04f;
        float dt  = binv - miu;
        float tg  = EXP2F(((-0.5f / var) * LOG2E_F) * (dt * dt));
        if (lane >= BINS) { kde = 0.f; tg = 0.f; }
        float sv = kde * rsqrtf(TWO_PI_F * vs);
        float tt = tg  * rsqrtf(TWO_PI_F * var);
        float ssum = sv, tsum = tt;
        #pragma unroll
        for (int off = 32; off; off >>= 1) {
            ssum += __shfl_xor(ssum, off, 64);
            tsum += __shfl_xor(tsum, off, 64);
        }
        float hist  = sv / fmaxf(ssum, 1e-12f);
        float tnorm = tt / tsum;
        float diff  = hist - tnorm;
        float ad    = fabsf(diff);
        float sl1   = (ad < 1.0f) ? 0.5f * diff * diff : (ad - 0.5f);
        if (lane >= BINS) sl1 = 0.f;
        #pragma unroll
        for (int off = 32; off; off >>= 1) sl1 += __shfl_xor(sl1, off, 64);
        if (lane == 0) partial[(c - 1) * NFEAT + f] = sl1;
    }

    // ---- finale: R4-proven ticket; last block reduces (deterministic f64) ----
    __threadfence();                              // release our partial/ncls stores
    __syncthreads();
    if (tid == 0) s_last = (atomicAdd(counter, 1) == NBLK - 1) ? 1 : 0;
    __syncthreads();
    if (s_last) {
        __threadfence();                          // acquire all blocks' stores
        double s = 0.0;
        for (int i = tid; i < NFEAT * (NCLS - 1); i += 128) s += (double)partial[i];
        #pragma unroll
        for (int off = 32; off; off >>= 1) s += __shfl_xor(s, off, 64);
        if (lane == 0) sd[wv] = s;
        __syncthreads();
        if (tid == 0) {
            double tot = sd[0] + sd[1];
            int active = 0;
            for (int cc = 1; cc < NCLS; ++cc) active += (ncls[cc] > 0) ? 1 : 0;
            double loss = tot / (double)(NFEAT * BINS) / ((double)active + 1e-12);
            out[0] = (float)loss;
        }
    }
}

extern "C" void kernel_launch(void* const* d_in, const int* in_sizes, int n_in,
                              void* d_out, int out_size, void* d_ws, size_t ws_size,
                              hipStream_t stream) {
    const float* x   = (const float*)d_in[0];
    const int*   lab = (const int*)d_in[1];
    float* out       = (float*)d_out;
    float* partial   = (float*)d_ws;
    int*   ncls      = (int*)((char*)d_ws + 18432);
    int*   counter   = (int*)((char*)d_ws + 18688);

    (void)hipMemsetAsync(counter, 0, sizeof(int), stream);   // ticket reset each replay
    hipLaunchKernelGGL(hist_main, dim3(NFEAT, 9), dim3(128), 0, stream,
                       x, lab, partial, ncls, counter, out);
}

// Round 9
// 29.347 us; speedup vs baseline: 3.3804x; 3.3804x over previous
//
#include <hip/hip_runtime.h>

#define NCLS 19
#define BINS 51
#define NPIX 4096
#define NFEAT 256
#define HALF 2048                  // pixels per wave
#define CAP 1024
#define SCROFF (CAP + 4)           // scratch slot base within a wave's segment
#define SEG (CAP + 4 + 64)         // 1092 floats per wave segment
#define TWO_PI_F 6.2831853071795864769f
#define LOG2E_F 1.4426950408889634f
#define EXP2F(v) __builtin_amdgcn_exp2f(v)

#define ST_AGENT(p, v) __hip_atomic_store((p), (v), __ATOMIC_RELAXED, __HIP_MEMORY_SCOPE_AGENT)
#define LD_AGENT(p)    __hip_atomic_load((p), __ATOMIC_RELAXED, __HIP_MEMORY_SCOPE_AGENT)

__device__ __forceinline__ unsigned mbcnt64(unsigned long long m) {
    unsigned r = __builtin_amdgcn_mbcnt_lo((unsigned)m, 0u);
    return __builtin_amdgcn_mbcnt_hi((unsigned)(m >> 32), r);
}

// ws layout: float partial[18*NFEAT] @ 0 (18432B); int ncls[32] @ 18432
__global__ __launch_bounds__(128)
void hist_main(const float* __restrict__ x, const int* __restrict__ lab,
               float* __restrict__ partial, int* __restrict__ ncls) {
    const int f    = blockIdx.x;
    const int cm1  = blockIdx.y;                  // 0..17
    const int c    = cm1 + 1;
    const int lane = threadIdx.x & 63;
    const int wv   = threadIdx.x >> 6;            // 0..1: each wave owns half the pixels

    __shared__ __align__(16) float xs[2][SEG];
    __shared__ float sh_s1[2], sh_s2[2];
    __shared__ int   sh_n[2];
    __shared__ float s_acc[2][64];

    float* xsw = xs[wv];
    const int4*   labv = (const int4*)lab + wv * (HALF / 4);
    const float4* xvec = (const float4*)(x + (size_t)f * NPIX) + wv * (HALF / 4);

    // ---- fused scan of own half: ballot-rank compaction + masked stats ----
    unsigned cnt = 0;
    float s1 = 0.f, s2 = 0.f;

#define SUBPX0(L, V)                                                  \
    {                                                                 \
        bool in = ((L) == c);                                         \
        unsigned long long m = __ballot(in);                          \
        unsigned g = cnt + mbcnt64(m);                                \
        int slot = (in && g < CAP) ? (int)g : (SCROFF + lane);        \
        xsw[slot] = (V);                                              \
        cnt += (unsigned)__popcll(m);                                 \
        float msk = in ? (V) : 0.f;                                   \
        s1 += msk;                                                    \
        s2 = fmaf(msk, (V), s2);                                      \
    }

    #pragma unroll
    for (int it = 0; it < HALF / 256; ++it) {     // 8 iters
        int4   lv = labv[it * 64 + lane];
        float4 vv = xvec[it * 64 + lane];
        SUBPX0(lv.x, vv.x)
        SUBPX0(lv.y, vv.y)
        SUBPX0(lv.z, vv.z)
        SUBPX0(lv.w, vv.w)
    }
#undef SUBPX0

    #pragma unroll
    for (int off = 32; off; off >>= 1) {
        s1 += __shfl_xor(s1, off, 64);
        s2 += __shfl_xor(s2, off, 64);
    }
    if (lane == 0) { sh_n[wv] = (int)cnt; sh_s1[wv] = s1; sh_s2[wv] = s2; }
    __syncthreads();                              // barrier 1: share stats

    const int n_tot = sh_n[0] + sh_n[1];
    if (f == 0 && threadIdx.x == 0) ST_AGENT(&ncls[c], n_tot);
    if (n_tot == 0) {                             // block-uniform: safe early-out
        if (threadIdx.x == 0) ST_AGENT(&partial[cm1 * NFEAT + f], 0.f);
        return;
    }

    const float fn  = (float)n_tot;
    const float miu = (sh_s1[0] + sh_s1[1]) / fn;
    const float var = fmaxf((sh_s2[0] + sh_s2[1]) / fn - miu * miu, 1e-12f);

    // ---- KDE over own compacted half: lane = bin; 4 exp2 chains ----
    const float binv  = -5.0f + 0.2f * (float)lane;
    const float coef2 = (-12.5f / var) * LOG2E_F;     // -0.5/(var*0.04)*log2e
    float a0 = 0.f, a1 = 0.f, a2 = 0.f, a3 = 0.f;

    for (unsigned t0 = 0; t0 < cnt; t0 += CAP) {
        if (t0 > 0) {                             // rare window rescan (cnt > CAP)
            unsigned c2 = 0;
            for (int it = 0; it < HALF / 256; ++it) {
                int4   lv = labv[it * 64 + lane];
                float4 vv = xvec[it * 64 + lane];
#define SUBPXW(L, V)                                                  \
    {                                                                 \
        bool in = ((L) == c);                                         \
        unsigned long long m = __ballot(in);                          \
        unsigned g = c2 + mbcnt64(m) - t0;                            \
        int slot = (in && g < CAP) ? (int)g : (SCROFF + lane);        \
        xsw[slot] = (V);                                              \
        c2 += (unsigned)__popcll(m);                                  \
    }
                SUBPXW(lv.x, vv.x)
                SUBPXW(lv.y, vv.y)
                SUBPXW(lv.z, vv.z)
                SUBPXW(lv.w, vv.w)
#undef SUBPXW
            }
        }
        int ns  = (int)((cnt - t0 < CAP) ? (cnt - t0) : CAP);
        int ns4 = (ns + 3) & ~3;
        if (lane < ns4 - ns) xsw[ns + lane] = 1e19f;   // sentinel: exp2 -> 0
        for (int i = 0; i < ns4; i += 4) {
            float4 v = *(const float4*)&xsw[i];        // same-addr broadcast read
            float d0 = binv - v.x, d1 = binv - v.y, d2 = binv - v.z, d3 = binv - v.w;
            a0 += EXP2F(coef2 * (d0 * d0));
            a1 += EXP2F(coef2 * (d1 * d1));
            a2 += EXP2F(coef2 * (d2 * d2));
            a3 += EXP2F(coef2 * (d3 * d3));
        }
    }
    s_acc[wv][lane] = (a0 + a1) + (a2 + a3);
    __syncthreads();                              // barrier 2: combine halves

    if (wv == 0) {
        float kde = s_acc[0][lane] + s_acc[1][lane];
        float vs  = var * 0.04f;
        float dt  = binv - miu;
        float tg  = EXP2F(((-0.5f / var) * LOG2E_F) * (dt * dt));
        if (lane >= BINS) { kde = 0.f; tg = 0.f; }
        float sv = kde * rsqrtf(TWO_PI_F * vs);
        float tt = tg  * rsqrtf(TWO_PI_F * var);
        float ssum = sv, tsum = tt;
        #pragma unroll
        for (int off = 32; off; off >>= 1) {
            ssum += __shfl_xor(ssum, off, 64);
            tsum += __shfl_xor(tsum, off, 64);
        }
        float hist  = sv / fmaxf(ssum, 1e-12f);
        float tnorm = tt / tsum;
        float diff  = hist - tnorm;
        float ad    = fabsf(diff);
        float sl1   = (ad < 1.0f) ? 0.5f * diff * diff : (ad - 0.5f);
        if (lane >= BINS) sl1 = 0.f;
        #pragma unroll
        for (int off = 32; off; off >>= 1) sl1 += __shfl_xor(sl1, off, 64);
        if (lane == 0) ST_AGENT(&partial[cm1 * NFEAT + f], sl1);
    }
}

// ---- deterministic f64 final reduction (agent-scope coherent loads) ----
__global__ __launch_bounds__(256)
void hist_final(const float* __restrict__ partial, const int* __restrict__ ncls,
                float* __restrict__ out) {
    const int tid = threadIdx.x, lane = tid & 63, wave = tid >> 6;
    __shared__ double sd[4];

    double s = 0.0;
    for (int i = tid; i < NFEAT * (NCLS - 1); i += 256)
        s += (double)LD_AGENT(&partial[i]);
    #pragma unroll
    for (int off = 32; off; off >>= 1) s += __shfl_xor(s, off, 64);
    if (lane == 0) sd[wave] = s;
    __syncthreads();
    if (tid == 0) {
        double tot = sd[0] + sd[1] + sd[2] + sd[3];
        int active = 0;
        for (int cc = 1; cc < NCLS; ++cc) active += (LD_AGENT(&ncls[cc]) > 0) ? 1 : 0;
        double loss = tot / (double)(NFEAT * BINS) / ((double)active + 1e-12);
        out[0] = (float)loss;
    }
}

extern "C" void kernel_launch(void* const* d_in, const int* in_sizes, int n_in,
                              void* d_out, int out_size, void* d_ws, size_t ws_size,
                              hipStream_t stream) {
    const float* x   = (const float*)d_in[0];
    const int*   lab = (const int*)d_in[1];
    float* out       = (float*)d_out;
    float* partial   = (float*)d_ws;
    int*   ncls      = (int*)((char*)d_ws + 18432);

    hipLaunchKernelGGL(hist_main, dim3(NFEAT, NCLS - 1), dim3(128), 0, stream,
                       x, lab, partial, ncls);
    hipLaunchKernelGGL(hist_final, dim3(1), dim3(256), 0, stream,
                       partial, ncls, out);
}

// Round 10
// 29.076 us; speedup vs baseline: 3.4120x; 1.0093x over previous
//
#include <hip/hip_runtime.h>

#define NCLS 19
#define BINS 51
#define NPIX 4096
#define NFEAT 256
#define VCAP 1024                  // staged values per wave (tiling beyond)
#define TWO_PI_F 6.2831853071795864769f
#define LOG2E_F 1.4426950408889634f
#define EXP2F(v) __builtin_amdgcn_exp2f(v)

#define ST_AGENT(p, v) __hip_atomic_store((p), (v), __ATOMIC_RELAXED, __HIP_MEMORY_SCOPE_AGENT)
#define LD_AGENT(p)    __hip_atomic_load((p), __ATOMIC_RELAXED, __HIP_MEMORY_SCOPE_AGENT)

__device__ __forceinline__ unsigned mbcnt64(unsigned long long m) {
    unsigned r = __builtin_amdgcn_mbcnt_lo((unsigned)m, 0u);
    return __builtin_amdgcn_mbcnt_hi((unsigned)(m >> 32), r);
}

// ws layout: float partial[18*NFEAT] @ 0 (18432B); int ncls[32] @ 18432
__global__ __launch_bounds__(256)
void hist_main(const float* __restrict__ x, const int* __restrict__ lab,
               float* __restrict__ partial, int* __restrict__ ncls) {
    const int cm1  = blockIdx.y;                  // 0..17
    const int c    = cm1 + 1;
    const int tid  = threadIdx.x;
    const int lane = tid & 63;
    const int wv   = tid >> 6;                    // 0..3

    __shared__ int   idx_lds[4 * 1024];           // class-c pixel indices, 4 segments
    __shared__ __align__(16) float val[4 * VCAP]; // per-wave value stage
    __shared__ int   n_sh[4];

    // ---- Phase 1: cooperative scan — wave wv compacts its 1024-pixel quarter ----
    const int4* labv = (const int4*)lab;
    int* myidx = &idx_lds[wv * 1024];
    unsigned cnt = 0;

#define SUBSCAN(L, S)                                                 \
    {                                                                 \
        bool in = ((L) == c);                                         \
        unsigned long long m = __ballot(in);                          \
        if (in) myidx[cnt + mbcnt64(m)] = pbase + (S);                \
        cnt += (unsigned)__popcll(m);                                 \
    }

    #pragma unroll
    for (int it = 0; it < 4; ++it) {
        int b4    = wv * 256 + it * 64 + lane;    // int4 index
        int4 lv   = labv[b4];
        int pbase = b4 * 4;
        SUBSCAN(lv.x, 0)
        SUBSCAN(lv.y, 1)
        SUBSCAN(lv.z, 2)
        SUBSCAN(lv.w, 3)
    }
#undef SUBSCAN

    if (lane == 0) n_sh[wv] = (int)cnt;
    __syncthreads();                              // the only barrier

    const int n0 = n_sh[0], n1 = n_sh[1], n2 = n_sh[2], n3 = n_sh[3];
    const int n  = n0 + n1 + n2 + n3;             // block-uniform
    const int f  = blockIdx.x * 4 + wv;           // this wave's feature

    if (blockIdx.x == 0 && tid == 0) ST_AGENT(&ncls[c], n);
    if (n == 0) {
        if (lane == 0) ST_AGENT(&partial[cm1 * NFEAT + f], 0.f);
        return;
    }

    // ---- Phase 2 (per wave): gather feature row via idx + fused stats ----
    const float* xrow = x + (size_t)f * NPIX;
    float* myval = &val[wv * VCAP];
    float s1 = 0.f, s2 = 0.f;
    {
        int pos = 0;
        #pragma unroll
        for (int s = 0; s < 4; ++s) {
            int ns_ = n_sh[s];
            const int* seg = &idx_lds[s * 1024];
            for (int i = lane; i < ns_; i += 64) {
                float v = xrow[seg[i]];           // scattered, L2-resident
                int j = pos + i;
                if (j < VCAP) myval[j] = v;
                s1 += v;
                s2 = fmaf(v, v, s2);
            }
            pos += ns_;
        }
    }
    #pragma unroll
    for (int off = 32; off; off >>= 1) {
        s1 += __shfl_xor(s1, off, 64);
        s2 += __shfl_xor(s2, off, 64);
    }
    const float fn  = (float)n;
    const float miu = s1 / fn;
    const float var = fmaxf(s2 / fn - miu * miu, 1e-12f);

    // ---- Phase 3 (per wave): KDE, lane = bin, poly-fma form, 4 exp2 chains ----
    const float binv = -5.0f + 0.2f * (float)lane;
    const float cu   = (-12.5f / var) * LOG2E_F;  // -0.5/(var*0.04)*log2e
    const float bl   = -2.f * cu * binv;
    const float al   = cu * binv * binv;          // arg = (cu*v+bl)*v+al = cu*(binv-v)^2
    float a0 = 0.f, a1 = 0.f, a2 = 0.f, a3 = 0.f;

    for (int t0 = 0; t0 < n; t0 += VCAP) {
        if (t0 > 0) {                             // rare re-gather tile (n > VCAP)
            int pos = 0;
            #pragma unroll
            for (int s = 0; s < 4; ++s) {
                int ns_ = n_sh[s];
                const int* seg = &idx_lds[s * 1024];
                for (int i = lane; i < ns_; i += 64) {
                    int j = pos + i - t0;
                    if (j >= 0 && j < VCAP) myval[j] = xrow[seg[i]];
                }
                pos += ns_;
            }
        }
        int ns  = n - t0; if (ns > VCAP) ns = VCAP;
        int ns4 = (ns + 3) & ~3;
        if (lane < ns4 - ns) myval[ns + lane] = 1e19f;   // sentinel: exp2 -> 0
        for (int i = 0; i < ns4; i += 4) {
            float4 v = *(const float4*)&myval[i];        // same-addr broadcast read
            a0 += EXP2F(fmaf(fmaf(cu, v.x, bl), v.x, al));
            a1 += EXP2F(fmaf(fmaf(cu, v.y, bl), v.y, al));
            a2 += EXP2F(fmaf(fmaf(cu, v.z, bl), v.z, al));
            a3 += EXP2F(fmaf(fmaf(cu, v.w, bl), v.w, al));
        }
    }

    // ---- Phase 4 (per wave): normalize + smooth-L1 ----
    float kde = (a0 + a1) + (a2 + a3);
    float vs  = var * 0.04f;
    float dt  = binv - miu;
    float tg  = EXP2F(((-0.5f / var) * LOG2E_F) * (dt * dt));
    if (lane >= BINS) { kde = 0.f; tg = 0.f; }
    float sv = kde * rsqrtf(TWO_PI_F * vs);
    float tt = tg  * rsqrtf(TWO_PI_F * var);
    float ssum = sv, tsum = tt;
    #pragma unroll
    for (int off = 32; off; off >>= 1) {
        ssum += __shfl_xor(ssum, off, 64);
        tsum += __shfl_xor(tsum, off, 64);
    }
    float hist  = sv / fmaxf(ssum, 1e-12f);
    float tnorm = tt / tsum;
    float diff  = hist - tnorm;
    float ad    = fabsf(diff);
    float sl1   = (ad < 1.0f) ? 0.5f * diff * diff : (ad - 0.5f);
    if (lane >= BINS) sl1 = 0.f;
    #pragma unroll
    for (int off = 32; off; off >>= 1) sl1 += __shfl_xor(sl1, off, 64);
    if (lane == 0) ST_AGENT(&partial[cm1 * NFEAT + f], sl1);
}

// ---- deterministic f64 final reduction (agent-scope coherent loads) ----
__global__ __launch_bounds__(256)
void hist_final(const float* __restrict__ partial, const int* __restrict__ ncls,
                float* __restrict__ out) {
    const int tid = threadIdx.x, lane = tid & 63, wave = tid >> 6;
    __shared__ double sd[4];

    double s = 0.0;
    for (int i = tid; i < NFEAT * (NCLS - 1); i += 256)
        s += (double)LD_AGENT(&partial[i]);
    #pragma unroll
    for (int off = 32; off; off >>= 1) s += __shfl_xor(s, off, 64);
    if (lane == 0) sd[wave] = s;
    __syncthreads();
    if (tid == 0) {
        double tot = sd[0] + sd[1] + sd[2] + sd[3];
        int active = 0;
        for (int cc = 1; cc < NCLS; ++cc) active += (LD_AGENT(&ncls[cc]) > 0) ? 1 : 0;
        double loss = tot / (double)(NFEAT * BINS) / ((double)active + 1e-12);
        out[0] = (float)loss;
    }
}

extern "C" void kernel_launch(void* const* d_in, const int* in_sizes, int n_in,
                              void* d_out, int out_size, void* d_ws, size_t ws_size,
                              hipStream_t stream) {
    const float* x   = (const float*)d_in[0];
    const int*   lab = (const int*)d_in[1];
    float* out       = (float*)d_out;
    float* partial   = (float*)d_ws;
    int*   ncls      = (int*)((char*)d_ws + 18432);

    hipLaunchKernelGGL(hist_main, dim3(NFEAT / 4, NCLS - 1), dim3(256), 0, stream,
                       x, lab, partial, ncls);
    hipLaunchKernelGGL(hist_final, dim3(1), dim3(256), 0, stream,
                       partial, ncls, out);
}

// Round 11
// 27.108 us; speedup vs baseline: 3.6597x; 1.0726x over previous
//
#include <hip/hip_runtime.h>

#define NCLS 19
#define BINS 51
#define NPIX 4096
#define NFEAT 256
#define VCAP 256                   // staged values per wave (chunked beyond)
#define NSLOT 16
#define TWO_PI_F 6.2831853071795864769f
#define LOG2E_F 1.4426950408889634f
#define EXP2F(v) __builtin_amdgcn_exp2f(v)

#define ST_AGENT(p, v) __hip_atomic_store((p), (v), __ATOMIC_RELAXED, __HIP_MEMORY_SCOPE_AGENT)
#define LD_AGENT(p)    __hip_atomic_load((p), __ATOMIC_RELAXED, __HIP_MEMORY_SCOPE_AGENT)

__device__ __forceinline__ unsigned mbcnt64(unsigned long long m) {
    unsigned r = __builtin_amdgcn_mbcnt_lo((unsigned)m, 0u);
    return __builtin_amdgcn_mbcnt_hi((unsigned)(m >> 32), r);
}

// ws layout: double slots[16] @ 0 (128 B, memset to 0 each launch); int ncls[32] @ 128
__global__ __launch_bounds__(256)
void hist_main(const float* __restrict__ x, const int* __restrict__ lab,
               double* __restrict__ slots, int* __restrict__ ncls) {
    const int cm1  = blockIdx.y;                  // 0..17
    const int c    = cm1 + 1;
    const int tid  = threadIdx.x;
    const int lane = tid & 63;
    const int wv   = tid >> 6;                    // 0..3

    __shared__ unsigned short idx_lds[4][1024];   // class-c pixel indices (u16), 8 KB
    __shared__ __align__(16) float val[4][VCAP + 8];
    __shared__ int   n_sh[4];
    __shared__ float s_loss[4];

    // ---- Phase 1: cooperative scan — wave wv compacts its 1024-pixel quarter ----
    const int4* labv = (const int4*)lab;
    unsigned short* myidx = idx_lds[wv];
    unsigned cnt = 0;

#define SUBSCAN(L, S)                                                 \
    {                                                                 \
        bool in = ((L) == c);                                         \
        unsigned long long m = __ballot(in);                          \
        if (in) myidx[cnt + mbcnt64(m)] = (unsigned short)(pbase + (S)); \
        cnt += (unsigned)__popcll(m);                                 \
    }

    #pragma unroll
    for (int it = 0; it < 4; ++it) {
        int b4    = wv * 256 + it * 64 + lane;
        int4 lv   = labv[b4];
        int pbase = b4 * 4;
        SUBSCAN(lv.x, 0)
        SUBSCAN(lv.y, 1)
        SUBSCAN(lv.z, 2)
        SUBSCAN(lv.w, 3)
    }
#undef SUBSCAN

    if (lane == 0) n_sh[wv] = (int)cnt;
    __syncthreads();                              // barrier 1

    const int n = n_sh[0] + n_sh[1] + n_sh[2] + n_sh[3];   // block-uniform
    const int f = blockIdx.x * 4 + wv;            // this wave's feature
    if (blockIdx.x == 0 && tid == 0) ST_AGENT(&ncls[c], n);
    if (n == 0) return;                           // contributes 0 — skip atomic

    // ---- Phase 2 (per wave): gather feature row + fused stats; stash chunk 0 ----
    const float* xrow  = x + (size_t)f * NPIX;
    float*       myval = val[wv];
    float s1 = 0.f, s2 = 0.f;
    {
        int pos = 0;
        #pragma unroll
        for (int s = 0; s < 4; ++s) {
            int ns_ = n_sh[s];
            const unsigned short* seg = idx_lds[s];
            for (int i = lane; i < ns_; i += 64) {
                float v = xrow[seg[i]];           // scattered, L2-resident
                int j = pos + i;
                if (j < VCAP) myval[j] = v;
                s1 += v;
                s2 = fmaf(v, v, s2);
            }
            pos += ns_;
        }
    }
    #pragma unroll
    for (int off = 32; off; off >>= 1) {
        s1 += __shfl_xor(s1, off, 64);
        s2 += __shfl_xor(s2, off, 64);
    }
    const float fn  = (float)n;
    const float miu = s1 / fn;
    const float var = fmaxf(s2 / fn - miu * miu, 1e-12f);

    // ---- Phase 3 (per wave): KDE, lane = bin, poly-fma, 4 exp2 chains ----
    const float binv = -5.0f + 0.2f * (float)lane;
    const float cu   = (-12.5f / var) * LOG2E_F;  // -0.5/(var*0.04)*log2e
    const float bl   = -2.f * cu * binv;
    const float al   = cu * binv * binv;          // arg = (cu*v+bl)*v+al
    float a0 = 0.f, a1 = 0.f, a2 = 0.f, a3 = 0.f;

    for (int t0 = 0; t0 < n; t0 += VCAP) {
        if (t0 > 0) {                             // rare re-gather chunk (n > VCAP)
            int pos = 0;
            #pragma unroll
            for (int s = 0; s < 4; ++s) {
                int ns_ = n_sh[s];
                const unsigned short* seg = idx_lds[s];
                for (int i = lane; i < ns_; i += 64) {
                    int j = pos + i - t0;
                    if (j >= 0 && j < VCAP) myval[j] = xrow[seg[i]];
                }
                pos += ns_;
            }
        }
        int ns  = n - t0; if (ns > VCAP) ns = VCAP;
        int ns4 = (ns + 3) & ~3;
        if (lane < ns4 - ns) myval[ns + lane] = 1e19f;   // sentinel: exp2 -> 0
        for (int i = 0; i < ns4; i += 4) {
            float4 v = *(const float4*)&myval[i];        // same-addr broadcast read
            a0 += EXP2F(fmaf(fmaf(cu, v.x, bl), v.x, al));
            a1 += EXP2F(fmaf(fmaf(cu, v.y, bl), v.y, al));
            a2 += EXP2F(fmaf(fmaf(cu, v.z, bl), v.z, al));
            a3 += EXP2F(fmaf(fmaf(cu, v.w, bl), v.w, al));
        }
    }

    // ---- Phase 4 (per wave): normalize + smooth-L1 ----
    float kde = (a0 + a1) + (a2 + a3);
    float vs  = var * 0.04f;
    float dt  = binv - miu;
    float tg  = EXP2F(((-0.5f / var) * LOG2E_F) * (dt * dt));
    if (lane >= BINS) { kde = 0.f; tg = 0.f; }
    float sv = kde * rsqrtf(TWO_PI_F * vs);
    float tt = tg  * rsqrtf(TWO_PI_F * var);
    float ssum = sv, tsum = tt;
    #pragma unroll
    for (int off = 32; off; off >>= 1) {
        ssum += __shfl_xor(ssum, off, 64);
        tsum += __shfl_xor(tsum, off, 64);
    }
    float hist  = sv / fmaxf(ssum, 1e-12f);
    float tnorm = tt / tsum;
    float diff  = hist - tnorm;
    float ad    = fabsf(diff);
    float sl1   = (ad < 1.0f) ? 0.5f * diff * diff : (ad - 0.5f);
    if (lane >= BINS) sl1 = 0.f;
    #pragma unroll
    for (int off = 32; off; off >>= 1) sl1 += __shfl_xor(sl1, off, 64);
    if (lane == 0) s_loss[wv] = sl1;
    __syncthreads();                              // barrier 2 (n>0: block-uniform)

    if (tid == 0) {
        float t = s_loss[0] + s_loss[1] + s_loss[2] + s_loss[3];
        atomicAdd(&slots[(blockIdx.y * 64 + blockIdx.x) & (NSLOT - 1)], (double)t);
    }
}

// ---- tiny finale: one wave sums 16 slots + counts active classes ----
__global__ __launch_bounds__(64)
void hist_final(const double* __restrict__ slots, const int* __restrict__ ncls,
                float* __restrict__ out) {
    const int lane = threadIdx.x & 63;
    double s = (lane < NSLOT) ? LD_AGENT(&slots[lane]) : 0.0;
    int    a = (lane >= 1 && lane < NCLS) ? ((LD_AGENT(&ncls[lane]) > 0) ? 1 : 0) : 0;
    #pragma unroll
    for (int off = 32; off; off >>= 1) {
        s += __shfl_xor(s, off, 64);
        a += __shfl_xor(a, off, 64);
    }
    if (lane == 0) {
        double loss = s / (double)(NFEAT * BINS) / ((double)a + 1e-12);
        out[0] = (float)loss;
    }
}

extern "C" void kernel_launch(void* const* d_in, const int* in_sizes, int n_in,
                              void* d_out, int out_size, void* d_ws, size_t ws_size,
                              hipStream_t stream) {
    const float* x   = (const float*)d_in[0];
    const int*   lab = (const int*)d_in[1];
    float* out       = (float*)d_out;
    double* slots    = (double*)d_ws;
    int*    ncls     = (int*)((char*)d_ws + 128);

    (void)hipMemsetAsync(slots, 0, NSLOT * sizeof(double), stream);  // per-replay reset
    hipLaunchKernelGGL(hist_main, dim3(NFEAT / 4, NCLS - 1), dim3(256), 0, stream,
                       x, lab, slots, ncls);
    hipLaunchKernelGGL(hist_final, dim3(1), dim3(64), 0, stream, slots, ncls, out);
}